// Round 16
// baseline (449.547 us; speedup 1.0000x reference)
//
#include <hip/hip_runtime.h>
#include <cstdint>
#include <cstddef>

// ---------------------------------------------------------------------------
// Performer block. fp32 in/out, bf16 MFMA internally.
// R16 = R15 (426us; vectorized bounce stores) + ONE change: BK 64->32 in
// gemm_tn. Staging LDS halves (union ~17.4KB for BN=128) -> ~6 blocks/CU
// (was 2-5, latency-bound). New 4-chunk swizzle: store c^(row>>1)&3, read
// (lk^(ar>>1))&3 -> <=2-way ds_read conflicts (free). Fused xd/D reductions
// re-indexed (4 chunks/row, shfl 1,2). gemm_kptv unchanged (proven).
// ws peak ~224 MB.
// ---------------------------------------------------------------------------

typedef __attribute__((ext_vector_type(8))) short s16x8;
typedef __attribute__((ext_vector_type(4))) short s16x4;
typedef __attribute__((ext_vector_type(4))) float fx4;
typedef __attribute__((ext_vector_type(8))) float fx8;

__device__ __forceinline__ float bf2f(short s) {
  union { float f; unsigned u; } z; z.u = ((unsigned)(unsigned short)s) << 16; return z.f;
}
__device__ __forceinline__ short f2bf(float f) {
  union { float f; unsigned u; } z; z.f = f;
  unsigned u = z.u;
  u += 0x7fffu + ((u >> 16) & 1u);   // RNE
  return (short)(u >> 16);
}

__device__ __forceinline__ void mfma_bf16(fx4& d, s16x8 a, s16x8 b) {
  asm("v_mfma_f32_16x16x32_bf16 %0, %1, %2, %0" : "+v"(d) : "v"(a), "v"(b));
}

enum : int { M_BIAS=1, M_EXP=2, M_DIV=4, M_RESID=8, M_GELU=16, M_TSTORE=32,
             M_BATCHBT=64, M_KQVT=128, M_RESIDT=256, M_F32OUT=512,
             M_XA=1024, M_DOTB=2048 };

// C[row][col] = sum_k A[row][k] * Bt[col][k]  (both operands k-contiguous bf16)
// Col-fast grid + bijective XCD chunk swizzle (nwg % 8 == 0).
// Staging: single-buffer BK=32 reg-staged LDS, 4-chunk XOR swizzle.
// Stores: LDS-bounce vectorized (R15 proven).
template<int BM, int BN, int MODE>
__global__ __launch_bounds__(256)
void gemm_tn(const short* __restrict__ A, int lda,
             const short* __restrict__ Bt, int ldbt, long btStride,
             short* __restrict__ C, int ldc,
             int K,
             const float* __restrict__ bias,
             const float* __restrict__ rowvec, float escale,
             const short* __restrict__ resid, int ldr, int rcol,
             short* __restrict__ vt)
{
  constexpr int WM = BM / 2, WN = BN / 2, MR = WM / 16, NR = WN / 16;
  constexpr int AIT = BM * 4 / 256, BIT = BN * 4 / 256;
  constexpr int PITCH = BN + 8;   // bounce row pitch (shorts / floats)

  __shared__ __align__(16) union UB {
    struct { short Al[BM][32]; short Bl[BN][32]; } s;
    short b16[64 * PITCH];
    float b32[32 * PITCH];
  } u;
  __shared__ float xdl[(MODE & (M_XA | M_DOTB)) ? BM : 1];

  const int tid = threadIdx.x;
  const int gx = gridDim.x;
  const int nwg = gx * gridDim.y;
  const int o = blockIdx.x + gx * blockIdx.y;        // hw dispatch order id
  const int swz = (o & 7) * (nwg >> 3) + (o >> 3);   // bijective for nwg%8==0
  const int bx = swz % gx, by = swz / gx;            // col fast within chunk
  const int row0 = by * BM, col0 = bx * BN;

  const short* Bt2 = (MODE & M_BATCHBT)
      ? Bt + (size_t)(row0 >> 13) * (size_t)btStride : Bt;
  const int w = tid >> 6, l = tid & 63;
  const int wr = w >> 1, wc = w & 1;
  const int lr = l & 15, lk = l >> 4;

  fx4 acc[MR][NR];
#pragma unroll
  for (int m = 0; m < MR; ++m)
#pragma unroll
    for (int n = 0; n < NR; ++n)
#pragma unroll
      for (int j = 0; j < 4; ++j) acc[m][n][j] = 0.0f;

  s16x8 areg[AIT], breg[BIT];
  float xacc[(MODE & (M_XA | M_DOTB)) ? AIT : 1];
#pragma unroll
  for (int i = 0; i < (int)(sizeof(xacc) / sizeof(float)); ++i) xacc[i] = 0.0f;

  auto loadA = [&](int kt) {
    const short* p = A + (size_t)row0 * lda + kt * 32;
#pragma unroll
    for (int i = 0; i < AIT; ++i) {
      int ch = i * 256 + tid;
      areg[i] = *(const s16x8*)(p + (size_t)(ch >> 2) * lda + ((ch & 3) * 8));
      if (MODE & M_XA) {
#pragma unroll
        for (int jj = 0; jj < 8; ++jj) { float f = bf2f(areg[i][jj]); xacc[i] += f * f; }
      }
      if (MODE & M_DOTB) {
        const float* dv = rowvec + (row0 >> 13) * 192 + kt * 32 + (ch & 3) * 8;
#pragma unroll
        for (int jj = 0; jj < 8; ++jj) xacc[i] += bf2f(areg[i][jj]) * dv[jj];
      }
    }
  };
  auto loadB = [&](int kt) {
    const short* p = Bt2 + (size_t)col0 * ldbt + kt * 32;
#pragma unroll
    for (int i = 0; i < BIT; ++i) {
      int ch = i * 256 + tid;
      breg[i] = *(const s16x8*)(p + (size_t)(ch >> 2) * ldbt + ((ch & 3) * 8));
    }
  };
  // swizzled LDS store: chunk (ch&3) ^ (row>>1), masked to 2 bits
  auto storeA = [&]() {
#pragma unroll
    for (int i = 0; i < AIT; ++i) {
      int ch = i * 256 + tid, row = ch >> 2;
      *(s16x8*)&u.s.Al[row][((ch ^ (row >> 1)) & 3) * 8] = areg[i];
    }
  };
  auto storeB = [&]() {
#pragma unroll
    for (int i = 0; i < BIT; ++i) {
      int ch = i * 256 + tid, row = ch >> 2;
      *(s16x8*)&u.s.Bl[row][((ch ^ (row >> 1)) & 3) * 8] = breg[i];
    }
  };

  const int NT = K / 32;
  loadA(0); loadB(0); storeA(); storeB();
  __syncthreads();
  for (int kt = 0; kt < NT; ++kt) {
    if (kt + 1 < NT) { loadA(kt + 1); loadB(kt + 1); }
    {
      s16x8 af[MR], bfr[NR];
#pragma unroll
      for (int m = 0; m < MR; ++m) {
        const int ar = wr * WM + m * 16 + lr;
        af[m] = *(const s16x8*)&u.s.Al[ar][((lk ^ (ar >> 1)) & 3) * 8];
      }
#pragma unroll
      for (int n = 0; n < NR; ++n) {
        const int br = wc * WN + n * 16 + lr;
        bfr[n] = *(const s16x8*)&u.s.Bl[br][((lk ^ (br >> 1)) & 3) * 8];
      }
#pragma unroll
      for (int m = 0; m < MR; ++m)
#pragma unroll
        for (int n = 0; n < NR; ++n)
          mfma_bf16(acc[m][n], af[m], bfr[n]);
    }
    if (kt + 1 < NT) {
      __syncthreads();            // all reads of the buffer done
      storeA(); storeB();         // overwrite with next tile
      __syncthreads();            // stores visible
    }
  }

  // fused per-row reduction: 4 threads (consecutive tids) cover row r's chunks
  if (MODE & (M_XA | M_DOTB)) {
    __syncthreads();
#pragma unroll
    for (int i = 0; i < (int)(sizeof(xacc) / sizeof(float)); ++i) {
      float s = xacc[i];
      s += __shfl_xor(s, 1); s += __shfl_xor(s, 2);
      if ((tid & 3) == 0) xdl[i * 64 + (tid >> 2)] = (MODE & M_XA) ? 0.5f * s : s;
    }
    __syncthreads();
  }

  // epilogue value (C/D layout m89: col = lane&15, row = (lane>>4)*4 + j)
  auto val = [&](int m, int n, int j) -> float {
    const int gcol = col0 + wc * WN + n * 16 + lr;
    const int lrow = wr * WM + m * 16 + lk * 4 + j;
    const int grow = row0 + lrow;
    float v = acc[m][n][j] + ((MODE & M_BIAS) ? bias[gcol] : 0.0f);
    if (MODE & M_EXP)  v = expf(v - xdl[lrow]) * escale;
    if (MODE & M_DIV)  v = v / (xdl[lrow] + 1e-8f);
    if (MODE & M_GELU) v = 0.5f * v * (1.0f + erff(v * 0.70710678118654752f));
    if (MODE & M_RESID)  v += bf2f(resid[(size_t)grow * ldr + rcol + gcol]);
    if (MODE & M_RESIDT) v += bf2f(resid[((size_t)((grow >> 13) * ldr + gcol)) * 8192 + (grow & 8191)]);
    return v;
  };

  if constexpr (!(MODE & M_F32OUT)) {
    const bool tst = (MODE & M_TSTORE) || ((MODE & M_KQVT) && col0 >= 768);
    const int bb = row0 >> 13;
    const int tb0 = row0 & 8191;
#pragma unroll
    for (int p = 0; p < 2; ++p) {
      __syncthreads();
      if (wr == p) {
#pragma unroll
        for (int m = 0; m < MR; ++m)
#pragma unroll
          for (int n = 0; n < NR; ++n)
#pragma unroll
            for (int j = 0; j < 4; ++j) {
              const int rl = m * 16 + lk * 4 + j;          // 0..63
              int c = wc * WN + n * 16 + lr;               // 0..BN-1
              if (tst) c ^= ((rl >> 3) & 7) << 3;          // bank stagger
              u.b16[rl * PITCH + c] = f2bf(val(m, n, j));
            }
      }
      __syncthreads();
      if (!tst) {
        constexpr int CH = BN / 8;
#pragma unroll
        for (int i = 0; i < 64 * CH / 256; ++i) {
          const int uu = i * 256 + tid, row = uu / CH, ch = uu % CH;
          s16x8 vv = *(const s16x8*)&u.b16[row * PITCH + ch * 8];
          *(s16x8*)(C + (size_t)(row0 + p * 64 + row) * ldc + col0 + ch * 8) = vv;
        }
      } else {
#pragma unroll
        for (int i = 0; i < BN * 8 / 256; ++i) {
          const int uu = i * 256 + tid, c = uu >> 3, rc = uu & 7;
          s16x8 vv;
#pragma unroll
          for (int k = 0; k < 8; ++k) {
            const int rl = rc * 8 + k;
            vv[k] = u.b16[rl * PITCH + (c ^ ((((rl) >> 3) & 7) << 3))];
          }
          const size_t rowsel = (MODE & M_TSTORE)
              ? (size_t)(bb * ldc + col0 + c)              // kp^T rows (m)
              : (size_t)(bb * 384 + (col0 - 768) + c);     // VT rows (n)
          short* dst = ((MODE & M_TSTORE) ? C : vt) + rowsel * 8192 + tb0 + p * 64 + rc * 8;
          *(s16x8*)dst = vv;
        }
      }
    }
  } else {
    // fp32 output: four 32-row passes, full fp32 precision
#pragma unroll
    for (int p = 0; p < 4; ++p) {
      __syncthreads();
      if (wr == (p >> 1)) {
#pragma unroll
        for (int mm = 0; mm < 2; ++mm) {
          const int m = (p & 1) * 2 + mm;
#pragma unroll
          for (int n = 0; n < NR; ++n)
#pragma unroll
            for (int j = 0; j < 4; ++j)
              u.b32[(mm * 16 + lk * 4 + j) * PITCH + wc * WN + n * 16 + lr] = val(m, n, j);
        }
      }
      __syncthreads();
      constexpr int CH = BN / 8;
#pragma unroll
      for (int i = 0; i < 32 * CH / 256; ++i) {
        const int uu = i * 256 + tid, row = uu / CH, ch = uu % CH;
        fx4 v0 = *(const fx4*)&u.b32[row * PITCH + ch * 8];
        fx4 v1 = *(const fx4*)&u.b32[row * PITCH + ch * 8 + 4];
        float* dst = (float*)C + (size_t)(row0 + p * 32 + row) * ldc + col0 + ch * 8;
        *(fx4*)dst = v0;
        *(fx4*)(dst + 4) = v1;
      }
    }
  }
}

// kptv partials: part[z=b*8+s][n][m] = sum_{t in split s} v[t,n]*kp[t,m]
__global__ __launch_bounds__(256)
void gemm_kptv(const short* __restrict__ vT, const short* __restrict__ kpT,
               float* __restrict__ part)
{
  __shared__ __align__(16) short Al[128][64];
  __shared__ __align__(16) short Bl[64][64];
  const int tid = threadIdx.x;
  const int b = blockIdx.z >> 3, s = blockIdx.z & 7;
  const int row0 = blockIdx.x * 128, col0 = blockIdx.y * 64;
  const short* A  = vT  + ((size_t)(b * 384 + row0)) * 8192 + s * 1024;
  const short* Bt = kpT + ((size_t)(b * 192 + col0)) * 8192 + s * 1024;
  const int w = tid >> 6, l = tid & 63;
  const int wr = w >> 1, wc = w & 1, lr = l & 15, lk = l >> 4;

  fx4 acc[4][2];
#pragma unroll
  for (int m = 0; m < 4; ++m)
#pragma unroll
    for (int n = 0; n < 2; ++n)
#pragma unroll
      for (int j = 0; j < 4; ++j) acc[m][n][j] = 0.0f;

  s16x8 areg[4], breg[2];
  auto loadA = [&](int kt) {
#pragma unroll
    for (int i = 0; i < 4; ++i) {
      int ch = i * 256 + tid;
      areg[i] = *(const s16x8*)(A + kt * 64 + (size_t)(ch >> 3) * 8192 + ((ch & 7) * 8));
    }
  };
  auto loadB = [&](int kt) {
#pragma unroll
    for (int i = 0; i < 2; ++i) {
      int ch = i * 256 + tid;
      breg[i] = *(const s16x8*)(Bt + kt * 64 + (size_t)(ch >> 3) * 8192 + ((ch & 7) * 8));
    }
  };
  auto storeA = [&]() {
#pragma unroll
    for (int i = 0; i < 4; ++i) {
      int ch = i * 256 + tid, row = ch >> 3;
      *(s16x8*)&Al[row][((ch ^ row) & 7) * 8] = areg[i];
    }
  };
  auto storeB = [&]() {
#pragma unroll
    for (int i = 0; i < 2; ++i) {
      int ch = i * 256 + tid, row = ch >> 3;
      *(s16x8*)&Bl[row][((ch ^ row) & 7) * 8] = breg[i];
    }
  };

  loadA(0); loadB(0); storeA(); storeB();
  __syncthreads();
  for (int kt = 0; kt < 16; ++kt) {
    if (kt + 1 < 16) { loadA(kt + 1); loadB(kt + 1); }
#pragma unroll
    for (int kk = 0; kk < 2; ++kk) {
      s16x8 af[4], bfr[2];
#pragma unroll
      for (int m = 0; m < 4; ++m) {
        const int ar = wr * 64 + m * 16 + lr;
        af[m] = *(const s16x8*)&Al[ar][(((kk * 4 + lk) ^ ar) & 7) * 8];
      }
#pragma unroll
      for (int n = 0; n < 2; ++n) {
        const int br = wc * 32 + n * 16 + lr;
        bfr[n] = *(const s16x8*)&Bl[br][(((kk * 4 + lk) ^ br) & 7) * 8];
      }
#pragma unroll
      for (int m = 0; m < 4; ++m)
#pragma unroll
        for (int n = 0; n < 2; ++n)
          mfma_bf16(acc[m][n], af[m], bfr[n]);
    }
    if (kt + 1 < 16) {
      __syncthreads();
      storeA(); storeB();
      __syncthreads();
    }
  }

  float* outp = part + (size_t)blockIdx.z * 73728;
#pragma unroll
  for (int m = 0; m < 4; ++m)
#pragma unroll
    for (int n = 0; n < 2; ++n) {
      const int gm = col0 + wc * 32 + n * 16 + lr;
#pragma unroll
      for (int j = 0; j < 4; ++j) {
        const int gn = row0 + wr * 64 + m * 16 + lk * 4 + j;
        outp[(size_t)gn * 192 + gm] = acc[m][n][j];
      }
    }
}

__global__ void kptv_reduce(const float* __restrict__ part, short* __restrict__ outb)
{
  const int i = blockIdx.x * 256 + threadIdx.x;   // i = b*73728 + n*192 + m
  const int b = i / 73728, j = i - b * 73728;
  const float* p = part + (size_t)b * 8 * 73728 + j;
  float s = 0.0f;
#pragma unroll
  for (int k = 0; k < 8; ++k) s += p[(size_t)k * 73728];
  outb[i] = f2bf(s);
}

// LayerNorm over 384, one wave per token.
template<typename T>
__global__ __launch_bounds__(256)
void ln_kernel(const T* __restrict__ in, const float* __restrict__ g,
               const float* __restrict__ bta, short* __restrict__ out)
{
  const int tid = threadIdx.x, w = tid >> 6, l = tid & 63;
  const size_t t = (size_t)blockIdx.x * 4 + w;
  float x[8]; float sum = 0.0f, ss = 0.0f;
  const bool act = l < 48;
  if (act) {
    if constexpr (sizeof(T) == 2) {
      s16x8 v = *(const s16x8*)((const short*)in + t * 384 + l * 8);
#pragma unroll
      for (int i = 0; i < 8; ++i) x[i] = bf2f(v[i]);
    } else {
      fx8 v = *(const fx8*)((const float*)in + t * 384 + l * 8);
#pragma unroll
      for (int i = 0; i < 8; ++i) x[i] = v[i];
    }
#pragma unroll
    for (int i = 0; i < 8; ++i) { sum += x[i]; ss += x[i] * x[i]; }
  }
#pragma unroll
  for (int d = 1; d < 64; d <<= 1) { sum += __shfl_xor(sum, d); ss += __shfl_xor(ss, d); }
  const float mu = sum * (1.0f / 384.0f);
  const float rs = rsqrtf(ss * (1.0f / 384.0f) - mu * mu + 1e-5f);
  if (act) {
    fx8 gv = *(const fx8*)(g + l * 8);
    fx8 bv = *(const fx8*)(bta + l * 8);
    s16x8 o;
#pragma unroll
    for (int i = 0; i < 8; ++i) o[i] = f2bf((x[i] - mu) * rs * gv[i] + bv[i]);
    *(s16x8*)(out + t * 384 + l * 8) = o;
  }
}

// kp_sum[b*192+m] = sum_t kpT[b][m][t]
__global__ __launch_bounds__(256)
void rowsum_kernel(const short* __restrict__ kpT, float* __restrict__ sum)
{
  const int tid = threadIdx.x;
  const short* row = kpT + (size_t)blockIdx.x * 8192;
  float s = 0.0f;
  for (int i = tid; i < 1024; i += 256) {
    s16x8 v = ((const s16x8*)row)[i];
#pragma unroll
    for (int k = 0; k < 8; ++k) s += bf2f(v[k]);
  }
#pragma unroll
  for (int d = 1; d < 64; d <<= 1) s += __shfl_xor(s, d);
  __shared__ float ps[4];
  if ((tid & 63) == 0) ps[tid >> 6] = s;
  __syncthreads();
  if (tid == 0) sum[blockIdx.x] = ps[0] + ps[1] + ps[2] + ps[3];
}

// dst[c][r] = f2bf(src[r][c]); fp32 -> bf16.
__global__ void transpose_kernel(const float* __restrict__ src, short* __restrict__ dst,
                                 int R, int Cc)
{
  __shared__ float tile[32][33];
  const int c0 = blockIdx.x * 32, r0 = blockIdx.y * 32;
  for (int i = threadIdx.y; i < 32; i += 8)
    tile[i][threadIdx.x] = src[(size_t)(r0 + i) * Cc + c0 + threadIdx.x];
  __syncthreads();
  for (int i = threadIdx.y; i < 32; i += 8)
    dst[(size_t)(c0 + i) * R + r0 + threadIdx.x] = f2bf(tile[threadIdx.x][i]);
}

__global__ void convert_kernel(const float* __restrict__ src, short* __restrict__ dst)
{
  const int i = blockIdx.x * 1024 + threadIdx.x * 4;
  fx4 v = *(const fx4*)(src + i);
  s16x4 o;
#pragma unroll
  for (int k = 0; k < 4; ++k) o[k] = f2bf(v[k]);
  *(s16x4*)(dst + i) = o;
}

extern "C" void kernel_launch(void* const* d_in, const int* in_sizes, int n_in,
                              void* d_out, int out_size, void* d_ws, size_t ws_size,
                              hipStream_t stream)
{
  const float* x      = (const float*)d_in[0];
  const float* w      = (const float*)d_in[1];   // [192][384], already k-contig
  const float* kqv_w  = (const float*)d_in[2];   // [384][1152]
  const float* kqv_b  = (const float*)d_in[3];
  const float* proj_w = (const float*)d_in[4];
  const float* proj_b = (const float*)d_in[5];
  const float* ln1_g  = (const float*)d_in[6];
  const float* ln1_b  = (const float*)d_in[7];
  const float* ln2_g  = (const float*)d_in[8];
  const float* ln2_b  = (const float*)d_in[9];
  const float* w1     = (const float*)d_in[10];
  const float* b1     = (const float*)d_in[11];
  const float* w2     = (const float*)d_in[12];
  const float* b2     = (const float*)d_in[13];

  char* p = (char*)d_ws;
  auto take = [&](size_t n) { char* r = p; p += (n + 255) & ~(size_t)255; return r; };
  short* wtKQV  = (short*)take(1152 * 384 * 2);
  short* wtPROJ = (short*)take(384 * 384 * 2);
  short* wtM1   = (short*)take(384 * 384 * 2);
  short* wtM2   = (short*)take(384 * 384 * 2);
  short* wB     = (short*)take(192 * 384 * 2);
  short* KQ     = (short*)take((size_t)65536 * 768 * 2);   // 100.7 MB; later YA, G
  short* VT     = (short*)take((size_t)8 * 384 * 8192 * 2); // 50.3 MB; later H2
  char*  KPQ    = take(50331648);                           // H -> (KPT|QP) -> Y
  float* KPSUM = (float*)take(1536 * 4);
  float* KPART = (float*)take((size_t)64 * 73728 * 4);      // 18.9 MB
  short* KPTVB = (short*)take(1179648);

  short* H   = (short*)KPQ;
  short* KPT = (short*)KPQ;
  short* QP  = (short*)(KPQ + 25165824);
  short* Y   = (short*)KPQ;
  short* YA  = KQ;   // KQ dead after qp gemm
  short* G   = KQ;   // YA dead after proj
  short* H2  = VT;   // VT dead after proj

  const float ESC = 0.07216878364870323f;  // 1/sqrt(192)
  dim3 blk(256);

  transpose_kernel<<<dim3(36, 12), dim3(32, 8), 0, stream>>>(kqv_w, wtKQV, 384, 1152);
  transpose_kernel<<<dim3(12, 12), dim3(32, 8), 0, stream>>>(proj_w, wtPROJ, 384, 384);
  transpose_kernel<<<dim3(12, 12), dim3(32, 8), 0, stream>>>(w1, wtM1, 384, 384);
  transpose_kernel<<<dim3(12, 12), dim3(32, 8), 0, stream>>>(w2, wtM2, 384, 384);
  convert_kernel<<<72, blk, 0, stream>>>(w, wB);

  // h = LN1(x)
  ln_kernel<float><<<16384, blk, 0, stream>>>(x, ln1_g, ln1_b, H);

  // kq + vT scatter = h @ kqv_w + b
  gemm_tn<128, 128, M_BIAS | M_KQVT><<<dim3(9, 512), blk, 0, stream>>>(
      H, 384, wtKQV, 384, 0, KQ, 768, 384, kqv_b, nullptr, 0.f, nullptr, 0, 0, VT);

  // kp^T[b][m][t] = exp(k@w^T - xd_k)/sqrt(m)   (xd fused via M_XA)
  gemm_tn<128, 64, M_EXP | M_TSTORE | M_XA><<<dim3(3, 512), blk, 0, stream>>>(
      KQ, 768, wB, 384, 0, KPT, 192, 384, nullptr, nullptr, ESC, nullptr, 0, 0, nullptr);
  // qp[t][m] = exp(q@w^T - xd_q)/sqrt(m)        (xd fused via M_XA)
  gemm_tn<128, 64, M_EXP | M_XA><<<dim3(3, 512), blk, 0, stream>>>(
      KQ + 384, 768, wB, 384, 0, QP, 192, 384, nullptr, nullptr, ESC, nullptr, 0, 0, nullptr);

  rowsum_kernel<<<1536, blk, 0, stream>>>(KPT, KPSUM);

  // kptv[b][n][m] via deterministic split-K partials
  gemm_kptv<<<dim3(3, 3, 64), blk, 0, stream>>>(VT, KPT, KPART);
  kptv_reduce<<<2304, blk, 0, stream>>>(KPART, KPTVB);

  // ya = (qp @ kptv^T) / (D + eps)   (D fused via M_DOTB with kpsum)
  gemm_tn<128, 128, M_DIV | M_BATCHBT | M_DOTB><<<dim3(3, 512), blk, 0, stream>>>(
      QP, 192, KPTVB, 192, 73728, YA, 384, 192, nullptr, KPSUM, 0.f, nullptr, 0, 0, nullptr);

  // y = v + ya @ proj_w + proj_b   (v residual read transposed from VT)
  gemm_tn<128, 128, M_BIAS | M_RESIDT><<<dim3(3, 512), blk, 0, stream>>>(
      YA, 384, wtPROJ, 384, 0, Y, 384, 384, proj_b, nullptr, 0.f, VT, 384, 0, nullptr);

  // h2 = LN2(y)
  ln_kernel<short><<<16384, blk, 0, stream>>>(Y, ln2_g, ln2_b, H2);

  // g = gelu(h2 @ w1 + b1)
  gemm_tn<128, 128, M_BIAS | M_GELU><<<dim3(3, 512), blk, 0, stream>>>(
      H2, 384, wtM1, 384, 0, G, 384, 384, b1, nullptr, 0.f, nullptr, 0, 0, nullptr);

  // out = y + g @ w2 + b2   (fp32 out)
  gemm_tn<128, 128, M_BIAS | M_RESID | M_F32OUT><<<dim3(3, 512), blk, 0, stream>>>(
      G, 384, wtM2, 384, 0, (short*)d_out, 384, 384, b2, nullptr, 0.f, Y, 384, 0, nullptr);
}

// Round 17
// 408.049 us; speedup vs baseline: 1.1017x; 1.1017x over previous
//
#include <hip/hip_runtime.h>
#include <cstdint>
#include <cstddef>

// ---------------------------------------------------------------------------
// Performer block. fp32 in/out, bf16 MFMA internally.
// R17 = R15 (426us best; R16's BK=32 reverted - barrier density beat
// occupancy) + launch merges: (a) 4 weight transposes + convert -> ONE
// prep_kernel; (b) kp+qp -> ONE dispatch (M_KPQP: bx<3 = qp row-major,
// bx>=3 = kp TSTORE; block-uniform runtime select of the proven R15 paths).
// ws peak ~224 MB.
// ---------------------------------------------------------------------------

typedef __attribute__((ext_vector_type(8))) short s16x8;
typedef __attribute__((ext_vector_type(4))) short s16x4;
typedef __attribute__((ext_vector_type(4))) float fx4;
typedef __attribute__((ext_vector_type(8))) float fx8;

__device__ __forceinline__ float bf2f(short s) {
  union { float f; unsigned u; } z; z.u = ((unsigned)(unsigned short)s) << 16; return z.f;
}
__device__ __forceinline__ short f2bf(float f) {
  union { float f; unsigned u; } z; z.f = f;
  unsigned u = z.u;
  u += 0x7fffu + ((u >> 16) & 1u);   // RNE
  return (short)(u >> 16);
}

__device__ __forceinline__ void mfma_bf16(fx4& d, s16x8 a, s16x8 b) {
  asm("v_mfma_f32_16x16x32_bf16 %0, %1, %2, %0" : "+v"(d) : "v"(a), "v"(b));
}

enum : int { M_BIAS=1, M_EXP=2, M_DIV=4, M_RESID=8, M_GELU=16, M_TSTORE=32,
             M_BATCHBT=64, M_KQVT=128, M_RESIDT=256, M_F32OUT=512,
             M_XA=1024, M_DOTB=2048, M_KPQP=8192 };

// C[row][col] = sum_k A[row][k] * Bt[col][k]  (both operands k-contiguous bf16)
// Col-fast grid + bijective XCD chunk swizzle (nwg % 8 == 0).
// Staging: single-buffer BK=64 reg-staged LDS with XOR chunk swizzle (R15).
// Stores: LDS-bounce vectorized (R15). M_KPQP: bx<3 -> qp, bx>=3 -> kp.
template<int BM, int BN, int MODE>
__global__ __launch_bounds__(256)
void gemm_tn(const short* __restrict__ A, int lda,
             const short* __restrict__ Bt, int ldbt, long btStride,
             short* __restrict__ C, int ldc,
             int K,
             const float* __restrict__ bias,
             const float* __restrict__ rowvec, float escale,
             const short* __restrict__ resid, int ldr, int rcol,
             short* __restrict__ vt)
{
  constexpr int WM = BM / 2, WN = BN / 2, MR = WM / 16, NR = WN / 16;
  constexpr int AIT = BM * 8 / 256, BIT = BN * 8 / 256;
  constexpr int PITCH = BN + 8;   // bounce row pitch (shorts / floats)

  __shared__ __align__(16) union UB {
    struct { short Al[BM][64]; short Bl[BN][64]; } s;
    short b16[64 * PITCH];
    float b32[32 * PITCH];
  } u;
  __shared__ float xdl[(MODE & (M_XA | M_DOTB)) ? BM : 1];

  const int tid = threadIdx.x;
  const int gx = gridDim.x;
  const int nwg = gx * gridDim.y;
  const int o = blockIdx.x + gx * blockIdx.y;        // hw dispatch order id
  const int swz = (o & 7) * (nwg >> 3) + (o >> 3);   // bijective for nwg%8==0
  const int bx = swz % gx, by = swz / gx;            // col fast within chunk
  const int row0 = by * BM;
  const bool qsel = (MODE & M_KPQP) ? (bx < 3) : false;
  const int col0 = (MODE & M_KPQP) ? (qsel ? bx : bx - 3) * BN : bx * BN;

  const short* A2 = ((MODE & M_KPQP) && qsel) ? A + 384 : A;
  const short* Bt2 = (MODE & M_BATCHBT)
      ? Bt + (size_t)(row0 >> 13) * (size_t)btStride : Bt;
  const int w = tid >> 6, l = tid & 63;
  const int wr = w >> 1, wc = w & 1;
  const int lr = l & 15, lk = l >> 4;

  fx4 acc[MR][NR];
#pragma unroll
  for (int m = 0; m < MR; ++m)
#pragma unroll
    for (int n = 0; n < NR; ++n)
#pragma unroll
      for (int j = 0; j < 4; ++j) acc[m][n][j] = 0.0f;

  s16x8 areg[AIT], breg[BIT];
  float xacc[(MODE & (M_XA | M_DOTB)) ? AIT : 1];
#pragma unroll
  for (int i = 0; i < (int)(sizeof(xacc) / sizeof(float)); ++i) xacc[i] = 0.0f;

  auto loadA = [&](int kt) {
    const short* p = A2 + (size_t)row0 * lda + kt * 64;
#pragma unroll
    for (int i = 0; i < AIT; ++i) {
      int ch = i * 256 + tid;
      areg[i] = *(const s16x8*)(p + (size_t)(ch >> 3) * lda + ((ch & 7) * 8));
      if (MODE & M_XA) {
#pragma unroll
        for (int jj = 0; jj < 8; ++jj) { float f = bf2f(areg[i][jj]); xacc[i] += f * f; }
      }
      if (MODE & M_DOTB) {
        const float* dv = rowvec + (row0 >> 13) * 192 + kt * 64 + (ch & 7) * 8;
#pragma unroll
        for (int jj = 0; jj < 8; ++jj) xacc[i] += bf2f(areg[i][jj]) * dv[jj];
      }
    }
  };
  auto loadB = [&](int kt) {
    const short* p = Bt2 + (size_t)col0 * ldbt + kt * 64;
#pragma unroll
    for (int i = 0; i < BIT; ++i) {
      int ch = i * 256 + tid;
      breg[i] = *(const s16x8*)(p + (size_t)(ch >> 3) * ldbt + ((ch & 7) * 8));
    }
  };
  // swizzled LDS store: chunk (ch&7) ^ (row&7)
  auto storeA = [&]() {
#pragma unroll
    for (int i = 0; i < AIT; ++i) {
      int ch = i * 256 + tid, row = ch >> 3;
      *(s16x8*)&u.s.Al[row][((ch ^ row) & 7) * 8] = areg[i];
    }
  };
  auto storeB = [&]() {
#pragma unroll
    for (int i = 0; i < BIT; ++i) {
      int ch = i * 256 + tid, row = ch >> 3;
      *(s16x8*)&u.s.Bl[row][((ch ^ row) & 7) * 8] = breg[i];
    }
  };

  const int NT = K / 64;
  loadA(0); loadB(0); storeA(); storeB();
  __syncthreads();
  for (int kt = 0; kt < NT; ++kt) {
    if (kt + 1 < NT) { loadA(kt + 1); loadB(kt + 1); }
#pragma unroll
    for (int kk = 0; kk < 2; ++kk) {
      s16x8 af[MR], bfr[NR];
#pragma unroll
      for (int m = 0; m < MR; ++m) {
        const int ar = wr * WM + m * 16 + lr;
        af[m] = *(const s16x8*)&u.s.Al[ar][(((kk * 4 + lk) ^ ar) & 7) * 8];
      }
#pragma unroll
      for (int n = 0; n < NR; ++n) {
        const int br = wc * WN + n * 16 + lr;
        bfr[n] = *(const s16x8*)&u.s.Bl[br][(((kk * 4 + lk) ^ br) & 7) * 8];
      }
#pragma unroll
      for (int m = 0; m < MR; ++m)
#pragma unroll
        for (int n = 0; n < NR; ++n)
          mfma_bf16(acc[m][n], af[m], bfr[n]);
    }
    if (kt + 1 < NT) {
      __syncthreads();            // all reads of the buffer done
      storeA(); storeB();         // overwrite with next tile
      __syncthreads();            // stores visible
    }
  }

  // fused per-row reduction: 8 threads (consecutive tids) cover row r's chunks
  if (MODE & (M_XA | M_DOTB)) {
    __syncthreads();
#pragma unroll
    for (int i = 0; i < (int)(sizeof(xacc) / sizeof(float)); ++i) {
      float s = xacc[i];
      s += __shfl_xor(s, 1); s += __shfl_xor(s, 2); s += __shfl_xor(s, 4);
      if ((tid & 7) == 0) xdl[i * 32 + (tid >> 3)] = (MODE & M_XA) ? 0.5f * s : s;
    }
    __syncthreads();
  }

  // epilogue value (C/D layout m89: col = lane&15, row = (lane>>4)*4 + j)
  auto val = [&](int m, int n, int j) -> float {
    const int gcol = col0 + wc * WN + n * 16 + lr;
    const int lrow = wr * WM + m * 16 + lk * 4 + j;
    const int grow = row0 + lrow;
    float v = acc[m][n][j] + ((MODE & M_BIAS) ? bias[gcol] : 0.0f);
    if (MODE & M_EXP)  v = expf(v - xdl[lrow]) * escale;
    if (MODE & M_DIV)  v = v / (xdl[lrow] + 1e-8f);
    if (MODE & M_GELU) v = 0.5f * v * (1.0f + erff(v * 0.70710678118654752f));
    if (MODE & M_RESID)  v += bf2f(resid[(size_t)grow * ldr + rcol + gcol]);
    if (MODE & M_RESIDT) v += bf2f(resid[((size_t)((grow >> 13) * ldr + gcol)) * 8192 + (grow & 8191)]);
    return v;
  };

  if constexpr (!(MODE & M_F32OUT)) {
    bool tst;
    if (MODE & M_KPQP) tst = !qsel;                          // kp -> transposed
    else tst = (MODE & M_TSTORE) || ((MODE & M_KQVT) && col0 >= 768);
    const int bb = row0 >> 13;
    const int tb0 = row0 & 8191;
#pragma unroll
    for (int p = 0; p < 2; ++p) {
      __syncthreads();
      if (wr == p) {
#pragma unroll
        for (int m = 0; m < MR; ++m)
#pragma unroll
          for (int n = 0; n < NR; ++n)
#pragma unroll
            for (int j = 0; j < 4; ++j) {
              const int rl = m * 16 + lk * 4 + j;          // 0..63
              int c = wc * WN + n * 16 + lr;               // 0..BN-1
              if (tst) c ^= ((rl >> 3) & 7) << 3;          // bank stagger
              u.b16[rl * PITCH + c] = f2bf(val(m, n, j));
            }
      }
      __syncthreads();
      if (!tst) {
        constexpr int CH = BN / 8;
#pragma unroll
        for (int i = 0; i < 64 * CH / 256; ++i) {
          const int uu = i * 256 + tid, row = uu / CH, ch = uu % CH;
          s16x8 vv = *(const s16x8*)&u.b16[row * PITCH + ch * 8];
          *(s16x8*)(C + (size_t)(row0 + p * 64 + row) * ldc + col0 + ch * 8) = vv;
        }
      } else {
#pragma unroll
        for (int i = 0; i < BN * 8 / 256; ++i) {
          const int uu = i * 256 + tid, c = uu >> 3, rc = uu & 7;
          s16x8 vv;
#pragma unroll
          for (int k = 0; k < 8; ++k) {
            const int rl = rc * 8 + k;
            vv[k] = u.b16[rl * PITCH + (c ^ ((((rl) >> 3) & 7) << 3))];
          }
          size_t rowsel;
          short* base;
          if (MODE & M_KPQP)       { rowsel = (size_t)(bb * 192 + col0 + c); base = vt; }
          else if (MODE & M_TSTORE){ rowsel = (size_t)(bb * ldc + col0 + c); base = C;  }
          else                     { rowsel = (size_t)(bb * 384 + (col0 - 768) + c); base = vt; }
          *(s16x8*)(base + rowsel * 8192 + tb0 + p * 64 + rc * 8) = vv;
        }
      }
    }
  } else {
    // fp32 output: four 32-row passes, full fp32 precision
#pragma unroll
    for (int p = 0; p < 4; ++p) {
      __syncthreads();
      if (wr == (p >> 1)) {
#pragma unroll
        for (int mm = 0; mm < 2; ++mm) {
          const int m = (p & 1) * 2 + mm;
#pragma unroll
          for (int n = 0; n < NR; ++n)
#pragma unroll
            for (int j = 0; j < 4; ++j)
              u.b32[(mm * 16 + lk * 4 + j) * PITCH + wc * WN + n * 16 + lr] = val(m, n, j);
        }
      }
      __syncthreads();
      constexpr int CH = BN / 8;
#pragma unroll
      for (int i = 0; i < 32 * CH / 256; ++i) {
        const int uu = i * 256 + tid, row = uu / CH, ch = uu % CH;
        fx4 v0 = *(const fx4*)&u.b32[row * PITCH + ch * 8];
        fx4 v1 = *(const fx4*)&u.b32[row * PITCH + ch * 8 + 4];
        float* dst = (float*)C + (size_t)(row0 + p * 32 + row) * ldc + col0 + ch * 8;
        *(fx4*)dst = v0;
        *(fx4*)(dst + 4) = v1;
      }
    }
  }
}

// kptv partials: part[z=b*8+s][n][m] = sum_{t in split s} v[t,n]*kp[t,m]
__global__ __launch_bounds__(256)
void gemm_kptv(const short* __restrict__ vT, const short* __restrict__ kpT,
               float* __restrict__ part)
{
  __shared__ __align__(16) short Al[128][64];
  __shared__ __align__(16) short Bl[64][64];
  const int tid = threadIdx.x;
  const int b = blockIdx.z >> 3, s = blockIdx.z & 7;
  const int row0 = blockIdx.x * 128, col0 = blockIdx.y * 64;
  const short* A  = vT  + ((size_t)(b * 384 + row0)) * 8192 + s * 1024;
  const short* Bt = kpT + ((size_t)(b * 192 + col0)) * 8192 + s * 1024;
  const int w = tid >> 6, l = tid & 63;
  const int wr = w >> 1, wc = w & 1, lr = l & 15, lk = l >> 4;

  fx4 acc[4][2];
#pragma unroll
  for (int m = 0; m < 4; ++m)
#pragma unroll
    for (int n = 0; n < 2; ++n)
#pragma unroll
      for (int j = 0; j < 4; ++j) acc[m][n][j] = 0.0f;

  s16x8 areg[4], breg[2];
  auto loadA = [&](int kt) {
#pragma unroll
    for (int i = 0; i < 4; ++i) {
      int ch = i * 256 + tid;
      areg[i] = *(const s16x8*)(A + kt * 64 + (size_t)(ch >> 3) * 8192 + ((ch & 7) * 8));
    }
  };
  auto loadB = [&](int kt) {
#pragma unroll
    for (int i = 0; i < 2; ++i) {
      int ch = i * 256 + tid;
      breg[i] = *(const s16x8*)(Bt + kt * 64 + (size_t)(ch >> 3) * 8192 + ((ch & 7) * 8));
    }
  };
  auto storeA = [&]() {
#pragma unroll
    for (int i = 0; i < 4; ++i) {
      int ch = i * 256 + tid, row = ch >> 3;
      *(s16x8*)&Al[row][((ch ^ row) & 7) * 8] = areg[i];
    }
  };
  auto storeB = [&]() {
#pragma unroll
    for (int i = 0; i < 2; ++i) {
      int ch = i * 256 + tid, row = ch >> 3;
      *(s16x8*)&Bl[row][((ch ^ row) & 7) * 8] = breg[i];
    }
  };

  loadA(0); loadB(0); storeA(); storeB();
  __syncthreads();
  for (int kt = 0; kt < 16; ++kt) {
    if (kt + 1 < 16) { loadA(kt + 1); loadB(kt + 1); }
#pragma unroll
    for (int kk = 0; kk < 2; ++kk) {
      s16x8 af[4], bfr[2];
#pragma unroll
      for (int m = 0; m < 4; ++m) {
        const int ar = wr * 64 + m * 16 + lr;
        af[m] = *(const s16x8*)&Al[ar][(((kk * 4 + lk) ^ ar) & 7) * 8];
      }
#pragma unroll
      for (int n = 0; n < 2; ++n) {
        const int br = wc * 32 + n * 16 + lr;
        bfr[n] = *(const s16x8*)&Bl[br][(((kk * 4 + lk) ^ br) & 7) * 8];
      }
#pragma unroll
      for (int m = 0; m < 4; ++m)
#pragma unroll
        for (int n = 0; n < 2; ++n)
          mfma_bf16(acc[m][n], af[m], bfr[n]);
    }
    if (kt + 1 < 16) {
      __syncthreads();
      storeA(); storeB();
      __syncthreads();
    }
  }

  float* outp = part + (size_t)blockIdx.z * 73728;
#pragma unroll
  for (int m = 0; m < 4; ++m)
#pragma unroll
    for (int n = 0; n < 2; ++n) {
      const int gm = col0 + wc * 32 + n * 16 + lr;
#pragma unroll
      for (int j = 0; j < 4; ++j) {
        const int gn = row0 + wr * 64 + m * 16 + lk * 4 + j;
        outp[(size_t)gn * 192 + gm] = acc[m][n][j];
      }
    }
}

__global__ void kptv_reduce(const float* __restrict__ part, short* __restrict__ outb)
{
  const int i = blockIdx.x * 256 + threadIdx.x;   // i = b*73728 + n*192 + m
  const int b = i / 73728, j = i - b * 73728;
  const float* p = part + (size_t)b * 8 * 73728 + j;
  float s = 0.0f;
#pragma unroll
  for (int k = 0; k < 8; ++k) s += p[(size_t)k * 73728];
  outb[i] = f2bf(s);
}

// LayerNorm over 384, one wave per token.
template<typename T>
__global__ __launch_bounds__(256)
void ln_kernel(const T* __restrict__ in, const float* __restrict__ g,
               const float* __restrict__ bta, short* __restrict__ out)
{
  const int tid = threadIdx.x, w = tid >> 6, l = tid & 63;
  const size_t t = (size_t)blockIdx.x * 4 + w;
  float x[8]; float sum = 0.0f, ss = 0.0f;
  const bool act = l < 48;
  if (act) {
    if constexpr (sizeof(T) == 2) {
      s16x8 v = *(const s16x8*)((const short*)in + t * 384 + l * 8);
#pragma unroll
      for (int i = 0; i < 8; ++i) x[i] = bf2f(v[i]);
    } else {
      fx8 v = *(const fx8*)((const float*)in + t * 384 + l * 8);
#pragma unroll
      for (int i = 0; i < 8; ++i) x[i] = v[i];
    }
#pragma unroll
    for (int i = 0; i < 8; ++i) { sum += x[i]; ss += x[i] * x[i]; }
  }
#pragma unroll
  for (int d = 1; d < 64; d <<= 1) { sum += __shfl_xor(sum, d); ss += __shfl_xor(ss, d); }
  const float mu = sum * (1.0f / 384.0f);
  const float rs = rsqrtf(ss * (1.0f / 384.0f) - mu * mu + 1e-5f);
  if (act) {
    fx8 gv = *(const fx8*)(g + l * 8);
    fx8 bv = *(const fx8*)(bta + l * 8);
    s16x8 o;
#pragma unroll
    for (int i = 0; i < 8; ++i) o[i] = f2bf((x[i] - mu) * rs * gv[i] + bv[i]);
    *(s16x8*)(out + t * 384 + l * 8) = o;
  }
}

// kp_sum[b*192+m] = sum_t kpT[b][m][t]
__global__ __launch_bounds__(256)
void rowsum_kernel(const short* __restrict__ kpT, float* __restrict__ sum)
{
  const int tid = threadIdx.x;
  const short* row = kpT + (size_t)blockIdx.x * 8192;
  float s = 0.0f;
  for (int i = tid; i < 1024; i += 256) {
    s16x8 v = ((const s16x8*)row)[i];
#pragma unroll
    for (int k = 0; k < 8; ++k) s += bf2f(v[k]);
  }
#pragma unroll
  for (int d = 1; d < 64; d <<= 1) s += __shfl_xor(s, d);
  __shared__ float ps[4];
  if ((tid & 63) == 0) ps[tid >> 6] = s;
  __syncthreads();
  if (tid == 0) sum[blockIdx.x] = ps[0] + ps[1] + ps[2] + ps[3];
}

// ONE prep kernel: 4 fp32->bf16 weight transposes + elementwise convert.
//   blocks [0,432): kqv_w 384x1152 ; [432,576): proj_w ; [576,720): w1 ;
//   [720,864): w2 (all 384x384) ; [864,936): convert w (192x384).
__global__ __launch_bounds__(256)
void prep_kernel(const float* __restrict__ kqv_w, const float* __restrict__ proj_w,
                 const float* __restrict__ w1, const float* __restrict__ w2,
                 const float* __restrict__ wsrc,
                 short* __restrict__ wtKQV, short* __restrict__ wtPROJ,
                 short* __restrict__ wtM1, short* __restrict__ wtM2,
                 short* __restrict__ wB)
{
  __shared__ float tile[32][33];
  int id = blockIdx.x;
  const int tid = threadIdx.x, tx = tid & 31, ty = tid >> 5;
  if (id >= 864) {                    // convert
    const int i = (id - 864) * 1024 + tid * 4;
    fx4 v = *(const fx4*)(wsrc + i);
    s16x4 o;
#pragma unroll
    for (int k = 0; k < 4; ++k) o[k] = f2bf(v[k]);
    *(s16x4*)(wB + i) = o;
    return;
  }
  const float* src; short* dst; int R, Cc, ncol;
  if (id < 432)      { src = kqv_w;  dst = wtKQV;  R = 384; Cc = 1152; ncol = 36; }
  else if (id < 576) { id -= 432; src = proj_w; dst = wtPROJ; R = 384; Cc = 384; ncol = 12; }
  else if (id < 720) { id -= 576; src = w1;     dst = wtM1;   R = 384; Cc = 384; ncol = 12; }
  else               { id -= 720; src = w2;     dst = wtM2;   R = 384; Cc = 384; ncol = 12; }
  const int c0 = (id % ncol) * 32, r0 = (id / ncol) * 32;
  for (int i = ty; i < 32; i += 8)
    tile[i][tx] = src[(size_t)(r0 + i) * Cc + c0 + tx];
  __syncthreads();
  for (int i = ty; i < 32; i += 8)
    dst[(size_t)(c0 + i) * R + r0 + tx] = f2bf(tile[tx][i]);
}

extern "C" void kernel_launch(void* const* d_in, const int* in_sizes, int n_in,
                              void* d_out, int out_size, void* d_ws, size_t ws_size,
                              hipStream_t stream)
{
  const float* x      = (const float*)d_in[0];
  const float* w      = (const float*)d_in[1];   // [192][384], already k-contig
  const float* kqv_w  = (const float*)d_in[2];   // [384][1152]
  const float* kqv_b  = (const float*)d_in[3];
  const float* proj_w = (const float*)d_in[4];
  const float* proj_b = (const float*)d_in[5];
  const float* ln1_g  = (const float*)d_in[6];
  const float* ln1_b  = (const float*)d_in[7];
  const float* ln2_g  = (const float*)d_in[8];
  const float* ln2_b  = (const float*)d_in[9];
  const float* w1     = (const float*)d_in[10];
  const float* b1     = (const float*)d_in[11];
  const float* w2     = (const float*)d_in[12];
  const float* b2     = (const float*)d_in[13];

  char* p = (char*)d_ws;
  auto take = [&](size_t n) { char* r = p; p += (n + 255) & ~(size_t)255; return r; };
  short* wtKQV  = (short*)take(1152 * 384 * 2);
  short* wtPROJ = (short*)take(384 * 384 * 2);
  short* wtM1   = (short*)take(384 * 384 * 2);
  short* wtM2   = (short*)take(384 * 384 * 2);
  short* wB     = (short*)take(192 * 384 * 2);
  short* KQ     = (short*)take((size_t)65536 * 768 * 2);   // 100.7 MB; later YA, G
  short* VT     = (short*)take((size_t)8 * 384 * 8192 * 2); // 50.3 MB; later H2
  char*  KPQ    = take(50331648);                           // H -> (KPT|QP) -> Y
  float* KPSUM = (float*)take(1536 * 4);
  float* KPART = (float*)take((size_t)64 * 73728 * 4);      // 18.9 MB
  short* KPTVB = (short*)take(1179648);

  short* H   = (short*)KPQ;
  short* KPT = (short*)KPQ;
  short* QP  = (short*)(KPQ + 25165824);
  short* Y   = (short*)KPQ;
  short* YA  = KQ;   // KQ dead after qp gemm
  short* G   = KQ;   // YA dead after proj
  short* H2  = VT;   // VT dead after proj

  const float ESC = 0.07216878364870323f;  // 1/sqrt(192)
  dim3 blk(256);

  // all weight prep in one launch
  prep_kernel<<<936, blk, 0, stream>>>(kqv_w, proj_w, w1, w2, w,
                                       wtKQV, wtPROJ, wtM1, wtM2, wB);

  // h = LN1(x)
  ln_kernel<float><<<16384, blk, 0, stream>>>(x, ln1_g, ln1_b, H);

  // kq + vT scatter = h @ kqv_w + b
  gemm_tn<128, 128, M_BIAS | M_KQVT><<<dim3(9, 512), blk, 0, stream>>>(
      H, 384, wtKQV, 384, 0, KQ, 768, 384, kqv_b, nullptr, 0.f, nullptr, 0, 0, VT);

  // kp^T (bx>=3, TSTORE->KPT) and qp (bx<3, row-major->QP) in ONE dispatch
  gemm_tn<128, 64, M_EXP | M_XA | M_KPQP><<<dim3(6, 512), blk, 0, stream>>>(
      KQ, 768, wB, 384, 0, QP, 192, 384, nullptr, nullptr, ESC, nullptr, 0, 0, KPT);

  rowsum_kernel<<<1536, blk, 0, stream>>>(KPT, KPSUM);

  // kptv[b][n][m] via deterministic split-K partials
  gemm_kptv<<<dim3(3, 3, 64), blk, 0, stream>>>(VT, KPT, KPART);
  kptv_reduce<<<2304, blk, 0, stream>>>(KPART, KPTVB);

  // ya = (qp @ kptv^T) / (D + eps)   (D fused via M_DOTB with kpsum)
  gemm_tn<128, 128, M_DIV | M_BATCHBT | M_DOTB><<<dim3(3, 512), blk, 0, stream>>>(
      QP, 192, KPTVB, 192, 73728, YA, 384, 192, nullptr, KPSUM, 0.f, nullptr, 0, 0, nullptr);

  // y = v + ya @ proj_w + proj_b   (v residual read transposed from VT)
  gemm_tn<128, 128, M_BIAS | M_RESIDT><<<dim3(3, 512), blk, 0, stream>>>(
      YA, 384, wtPROJ, 384, 0, Y, 384, 384, proj_b, nullptr, 0.f, VT, 384, 0, nullptr);

  // h2 = LN2(y)
  ln_kernel<short><<<16384, blk, 0, stream>>>(Y, ln2_g, ln2_b, H2);

  // g = gelu(h2 @ w1 + b1)
  gemm_tn<128, 128, M_BIAS | M_GELU><<<dim3(3, 512), blk, 0, stream>>>(
      H2, 384, wtM1, 384, 0, G, 384, 384, b1, nullptr, 0.f, nullptr, 0, 0, nullptr);

  // out = y + g @ w2 + b2   (fp32 out)
  gemm_tn<128, 128, M_BIAS | M_RESID | M_F32OUT><<<dim3(3, 512), blk, 0, stream>>>(
      G, 384, wtM2, 384, 0, (short*)d_out, 384, 384, b2, nullptr, 0.f, Y, 384, 0, nullptr);
}